// Round 7
// baseline (20431.836 us; speedup 1.0000x reference)
//
#include <hip/hip_runtime.h>

#define NN 25000
#define NE 200000
#define F 64
#define HD 192
#define NL 3
#define NB 8    // nodes per block in node_mlp
#define SE 16   // edges per block in encode_scatter_edges
#define FP (F + 1)

// edge_mlp tiling
#define EB2 16          // edges per block (32 vectors: real+imag)
#define KC 16           // k-chunk staged in LDS
#define WST 20          // LDS chunk row stride (20 floats: bank-balanced, 16B-aligned)
#define NCH (HD / KC)   // 12 chunks per 192-wide layer

typedef unsigned short bfu;

__device__ __forceinline__ float bf2f(bfu u) { return __uint_as_float(((unsigned)u) << 16); }
// dual-dtype float loads: isf32 is wave-uniform (runtime-detected)
__device__ __forceinline__ float loadf(const void* p, size_t i, int isf32) {
    return isf32 ? ((const float*)p)[i] : bf2f(((const bfu*)p)[i]);
}
__device__ __forceinline__ float4 load4(const void* p, size_t i4, int isf32) {
    if (isf32) return ((const float4*)p)[i4];
    ushort4 u = ((const ushort4*)p)[i4];
    return make_float4(bf2f(u.x), bf2f(u.y), bf2f(u.z), bf2f(u.w));
}

// ---- runtime metadata detection ----
// flags[0]: edge_index is int32 pairs (1) vs int64 values (0).
// flags[1]: float tensors are f32 (1) vs bf16 (0).
__global__ void detect_meta(const int* __restrict__ idx, const unsigned* __restrict__ fdata,
                            int* __restrict__ flags) {
    __shared__ int s_or[256];
    __shared__ int s_cnt[256];
    int t = threadIdx.x;
    int v = 0;
    for (int j = t; j < 4096; j += 256) v |= idx[2 * j + 1];
    int c = 0;
    for (int j = t; j < 2048; j += 256) {
        unsigned e = (fdata[j] >> 7) & 0xFFu;
        c += (e >= 100u && e <= 140u) ? 1 : 0;
    }
    s_or[t] = v; s_cnt[t] = c;
    __syncthreads();
    for (int s = 128; s > 0; s >>= 1) {
        if (t < s) { s_or[t] |= s_or[t + s]; s_cnt[t] += s_cnt[t + s]; }
        __syncthreads();
    }
    if (t == 0) { flags[0] = (s_or[0] != 0); flags[1] = (s_cnt[0] < 1024); }
}

__device__ __forceinline__ void load_edge(const int* __restrict__ idx, int i32flag, int e,
                                          int& row, int& col) {
    if (i32flag) { row = idx[2 * e]; col = idx[2 * e + 1]; }
    else         { row = idx[4 * e]; col = idx[4 * e + 2]; }
}

// ---- node encoder: xr[n,0:64] = node_real @ Wn^T + bn (likewise imag) ----
__global__ __launch_bounds__(256) void encode_nodes(
    const void* __restrict__ xr_in, const void* __restrict__ xi_in,
    const void* __restrict__ W, const void* __restrict__ b,
    const int* __restrict__ flags,
    float* __restrict__ xr, float* __restrict__ xi)
{
    __shared__ float Ws[F * FP];
    __shared__ float bs[F];
    __shared__ float xsr[4][F], xsi[4][F];
    int isf32 = flags[1];
    int t = threadIdx.y * 64 + threadIdx.x;
    for (int k = t; k < F * F; k += 256) Ws[(k >> 6) * FP + (k & 63)] = loadf(W, k, isf32);
    if (t < F) bs[t] = loadf(b, t, isf32);
    int n = blockIdx.x * 4 + threadIdx.y;
    int o = threadIdx.x;
    if (n < NN) {
        xsr[threadIdx.y][o] = loadf(xr_in, (size_t)n * F + o, isf32);
        xsi[threadIdx.y][o] = loadf(xi_in, (size_t)n * F + o, isf32);
    }
    __syncthreads();
    if (n >= NN) return;
    float ar = bs[o], ai = bs[o];
    const float* wrow = &Ws[o * FP];
    #pragma unroll 8
    for (int i = 0; i < F; i++) {
        ar += xsr[threadIdx.y][i] * wrow[i];
        ai += xsi[threadIdx.y][i] * wrow[i];
    }
    xr[(size_t)n * HD + o] = ar;
    xi[(size_t)n * HD + o] = ai;
}

// ---- fused edge encode + scatter:
//   xr[row,128+f] += (We@e+be)[f];  xr[row,64+f] += xr[col,f]  (cols 0:64 = encoded nodes)
__global__ __launch_bounds__(256) void encode_scatter_edges(
    const void* __restrict__ edge_real, const void* __restrict__ edge_imag,
    const void* __restrict__ We, const void* __restrict__ be,
    const int* __restrict__ idx, const int* __restrict__ flags,
    float* __restrict__ xr, float* __restrict__ xi)
{
    __shared__ float Ws[F * FP];
    __shared__ float bs[F];
    __shared__ float xinr[SE][F], xini[SE][F];
    __shared__ int rows[SE], cols[SE];
    int isf32 = flags[1];
    int t = threadIdx.x;
    int ebase = blockIdx.x * SE;
    for (int k = t; k < F * F; k += 256) Ws[(k >> 6) * FP + (k & 63)] = loadf(We, k, isf32);
    if (t < F) bs[t] = loadf(be, t, isf32);
    if (t < SE) {
        int r, c;
        load_edge(idx, flags[0], ebase + t, r, c);
        rows[t] = r; cols[t] = c;
    }
    for (int j = t; j < SE * F; j += 256) {
        int nb = j >> 6, f = j & 63;
        xinr[nb][f] = loadf(edge_real, (size_t)(ebase + nb) * F + f, isf32);
        xini[nb][f] = loadf(edge_imag, (size_t)(ebase + nb) * F + f, isf32);
    }
    __syncthreads();
    for (int j = t; j < SE * F; j += 256) {
        int nb = j >> 6, f = j & 63;
        float ar = bs[f], ai = bs[f];
        const float* wrow = &Ws[f * FP];
        #pragma unroll 8
        for (int i = 0; i < F; i++) {
            ar += wrow[i] * xinr[nb][i];
            ai += wrow[i] * xini[nb][i];
        }
        int row = rows[nb], col = cols[nb];
        atomicAdd(&xr[(size_t)row * HD + 128 + f], ar);
        atomicAdd(&xi[(size_t)row * HD + 128 + f], ai);
        atomicAdd(&xr[(size_t)row * HD + 64 + f], xr[(size_t)col * HD + f]);
        atomicAdd(&xi[(size_t)row * HD + 64 + f], xi[(size_t)col * HD + f]);
    }
}

// ---- node MLP: 8 nodes/block; writes h (f32) into d_out ----
__global__ __launch_bounds__(192) void node_mlp(
    const float* __restrict__ xr, const float* __restrict__ xi,
    const void* __restrict__ W, const void* __restrict__ b, const void* __restrict__ alpha,
    const void* __restrict__ Wout, const void* __restrict__ bout,
    const int* __restrict__ flags,
    float* __restrict__ o_hr, float* __restrict__ o_hi)
{
    __shared__ float xs[2 * NB][HD];
    int isf32 = flags[1];
    int t = threadIdx.x;
    int nbase = blockIdx.x * NB;
    for (int j = t; j < NB * HD; j += 192) {
        int nb = j / HD, f = j % HD;
        int n = nbase + nb;
        float vr = 0.f, vi = 0.f;
        if (n < NN) { vr = xr[(size_t)n * HD + f]; vi = xi[(size_t)n * HD + f]; }
        xs[nb][f] = vr; xs[NB + nb][f] = vi;
    }
    __syncthreads();
    for (int l = 0; l < NL; l++) {
        size_t base4 = ((size_t)l * HD * HD + (size_t)t * HD) >> 2;
        float bb = loadf(b, l * HD + t, isf32);
        float acc[2 * NB];
        #pragma unroll
        for (int v = 0; v < 2 * NB; v++) acc[v] = bb;
        #pragma unroll 2
        for (int k = 0; k < HD / 4; k++) {
            float4 w = load4(W, base4 + k, isf32);
            #pragma unroll
            for (int v = 0; v < 2 * NB; v++)
                acc[v] += xs[v][4 * k] * w.x + xs[v][4 * k + 1] * w.y
                        + xs[v][4 * k + 2] * w.z + xs[v][4 * k + 3] * w.w;
        }
        float a = loadf(alpha, l, isf32);
        __syncthreads();
        #pragma unroll
        for (int v = 0; v < 2 * NB; v++) { float x = acc[v]; xs[v][t] = x >= 0.f ? x : a * x; }
        __syncthreads();
    }
    if (t < F) {
        size_t base4 = ((size_t)t * HD) >> 2;
        float bb = loadf(bout, t, isf32);
        float acc[2 * NB];
        #pragma unroll
        for (int v = 0; v < 2 * NB; v++) acc[v] = bb;
        #pragma unroll 2
        for (int k = 0; k < HD / 4; k++) {
            float4 w = load4(Wout, base4 + k, isf32);
            #pragma unroll
            for (int v = 0; v < 2 * NB; v++)
                acc[v] += xs[v][4 * k] * w.x + xs[v][4 * k + 1] * w.y
                        + xs[v][4 * k + 2] * w.z + xs[v][4 * k + 3] * w.w;
        }
        #pragma unroll
        for (int nb = 0; nb < NB; nb++) {
            int n = nbase + nb;
            if (n < NN) {
                o_hr[(size_t)n * F + t] = acc[nb];
                o_hi[(size_t)n * F + t] = acc[NB + nb];
            }
        }
    }
}

// ---- edge MLP (register-tiled, LDS-staged weights) ----
// 256 threads, 16 edges (32 vectors) per block.
// thread (ox = t&63, vy = t>>6): owns outputs {ox, ox+64, ox+128} for vectors 8vy..8vy+7.
// Per k-quad/wave: 8 broadcast ds_read_b128 (x) + 3 bank-balanced ds_read_b128 (W) feed 96 FMAs.
// W staged from global in coalesced k-chunks of 16 (row stride 20 floats in LDS: 64 lanes touch
// each bank exactly 8x -> no serialization beyond the 1024B/128B floor).
// xs rows are wave-private after the prologue -> only the W chunk buffer needs barriers.
__global__ __launch_bounds__(256, 3) void edge_mlp(
    const void* __restrict__ edge_real, const void* __restrict__ edge_imag,
    const void* __restrict__ We, const void* __restrict__ be,
    const int* __restrict__ idx, const int* __restrict__ flags,
    const float* __restrict__ o_hr, const float* __restrict__ o_hi,
    const void* __restrict__ W, const void* __restrict__ b, const void* __restrict__ alpha,
    const void* __restrict__ Wout, const void* __restrict__ bout,
    float* __restrict__ outr, float* __restrict__ outi)
{
    __shared__ float Wbuf[F * FP];          // 4160 floats: encoder [64][65], then chunks [192][20]
    __shared__ float bs[F];
    __shared__ float xs[2 * EB2][HD];       // 32 x 192
    __shared__ float xin[2][EB2][F];
    __shared__ int rows[EB2], cols[EB2];
    int isf32 = flags[1];
    int t = threadIdx.x;
    int ebase = blockIdx.x * EB2;
    int vy = t >> 6;        // 0..3 : vector group (wave id)
    int ox = t & 63;        // 0..63: output lane

    // ---- prologue: encoder weights + inputs + edge indices ----
    for (int k = t; k < F * F; k += 256) Wbuf[(k >> 6) * FP + (k & 63)] = loadf(We, k, isf32);
    if (t < F) bs[t] = loadf(be, t, isf32);
    if (t < EB2) {
        int r, c;
        load_edge(idx, flags[0], ebase + t, r, c);
        rows[t] = r; cols[t] = c;
    }
    for (int j = t; j < EB2 * F; j += 256) {
        int nb = j >> 6, f = j & 63;
        xin[0][nb][f] = loadf(edge_real, (size_t)(ebase + nb) * F + f, isf32);
        xin[1][nb][f] = loadf(edge_imag, (size_t)(ebase + nb) * F + f, isf32);
    }
    __syncthreads();
    // encoded edge feats -> xs[:,0:64]; gathered h[row],h[col] -> xs[:,64:192]
    // vector v = 2*edge_local + (0 real / 1 imag)
    for (int j = t; j < EB2 * F; j += 256) {
        int nb = j >> 6, f = j & 63;
        float ar = bs[f], ai = bs[f];
        const float* wrow = &Wbuf[f * FP];
        #pragma unroll 8
        for (int i = 0; i < F; i++) {
            ar += wrow[i] * xin[0][nb][i];
            ai += wrow[i] * xin[1][nb][i];
        }
        int r = rows[nb], cc = cols[nb];
        xs[2 * nb][f]     = ar;
        xs[2 * nb + 1][f] = ai;
        xs[2 * nb][F + f]         = o_hr[(size_t)r * F + f];
        xs[2 * nb + 1][F + f]     = o_hi[(size_t)r * F + f];
        xs[2 * nb][2 * F + f]     = o_hr[(size_t)cc * F + f];
        xs[2 * nb + 1][2 * F + f] = o_hi[(size_t)cc * F + f];
    }
    // no explicit barrier: the first chunk barrier below orders prologue writes/reads.

    const float* xgrp = &xs[8 * vy][0];

    // ---- 3 hidden layers ----
    #pragma unroll 1
    for (int l = 0; l < NL; l++) {
        float acc0[8], acc1[8], acc2[8];
        {
            float b0 = loadf(b, l * HD + ox, isf32);
            float b1 = loadf(b, l * HD + ox + 64, isf32);
            float b2 = loadf(b, l * HD + ox + 128, isf32);
            #pragma unroll
            for (int j = 0; j < 8; j++) { acc0[j] = b0; acc1[j] = b1; acc2[j] = b2; }
        }
        #pragma unroll 1
        for (int c = 0; c < NCH; c++) {
            // stage chunk: rows 0..191, cols c*16..c*16+15 ; 3 float4 per thread, 64B segments
            size_t wb = (size_t)l * (HD * HD / 4) + (size_t)c * (KC / 4);
            float4 p0 = load4(W, wb + (size_t)((t      ) >> 2) * (HD / 4) + ((t      ) & 3), isf32);
            float4 p1 = load4(W, wb + (size_t)((t + 256) >> 2) * (HD / 4) + ((t + 256) & 3), isf32);
            float4 p2 = load4(W, wb + (size_t)((t + 512) >> 2) * (HD / 4) + ((t + 512) & 3), isf32);
            __syncthreads();   // previous chunk's readers done
            *(float4*)&Wbuf[((t      ) >> 2) * WST + ((t      ) & 3) * 4] = p0;
            *(float4*)&Wbuf[((t + 256) >> 2) * WST + ((t + 256) & 3) * 4] = p1;
            *(float4*)&Wbuf[((t + 512) >> 2) * WST + ((t + 512) & 3) * 4] = p2;
            __syncthreads();   // chunk ready
            const float* xb = xgrp + c * KC;
            #pragma unroll
            for (int k4 = 0; k4 < KC / 4; k4++) {
                float4 w0 = *(const float4*)&Wbuf[(ox      ) * WST + 4 * k4];
                float4 w1 = *(const float4*)&Wbuf[(ox +  64) * WST + 4 * k4];
                float4 w2 = *(const float4*)&Wbuf[(ox + 128) * WST + 4 * k4];
                #pragma unroll
                for (int j = 0; j < 8; j++) {
                    float4 xv = *(const float4*)(xb + j * HD + 4 * k4);
                    acc0[j] += xv.x * w0.x + xv.y * w0.y + xv.z * w0.z + xv.w * w0.w;
                    acc1[j] += xv.x * w1.x + xv.y * w1.y + xv.z * w1.z + xv.w * w1.w;
                    acc2[j] += xv.x * w2.x + xv.y * w2.y + xv.z * w2.z + xv.w * w2.w;
                }
            }
        }
        float a = loadf(alpha, l, isf32);
        #pragma unroll
        for (int j = 0; j < 8; j++) {     // xs rows 8vy..8vy+7 are wave-private: no barrier
            float x0 = acc0[j], x1 = acc1[j], x2 = acc2[j];
            xs[8 * vy + j][ox      ] = x0 >= 0.f ? x0 : a * x0;
            xs[8 * vy + j][ox +  64] = x1 >= 0.f ? x1 : a * x1;
            xs[8 * vy + j][ox + 128] = x2 >= 0.f ? x2 : a * x2;
        }
    }

    // ---- output layer: 64 outputs; thread (ox,vy) -> output ox of its 8 vectors ----
    float accO[8];
    {
        float bo = loadf(bout, ox, isf32);
        #pragma unroll
        for (int j = 0; j < 8; j++) accO[j] = bo;
    }
    #pragma unroll 1
    for (int c = 0; c < NCH; c++) {
        float4 p0 = load4(Wout, (size_t)(t >> 2) * (HD / 4) + (size_t)c * (KC / 4) + (t & 3), isf32);
        __syncthreads();
        *(float4*)&Wbuf[(t >> 2) * WST + (t & 3) * 4] = p0;
        __syncthreads();
        const float* xb = xgrp + c * KC;
        #pragma unroll
        for (int k4 = 0; k4 < KC / 4; k4++) {
            float4 w0 = *(const float4*)&Wbuf[ox * WST + 4 * k4];
            #pragma unroll
            for (int j = 0; j < 8; j++) {
                float4 xv = *(const float4*)(xb + j * HD + 4 * k4);
                accO[j] += xv.x * w0.x + xv.y * w0.y + xv.z * w0.z + xv.w * w0.w;
            }
        }
    }
    #pragma unroll
    for (int j = 0; j < 8; j++) {
        int v = 8 * vy + j;
        size_t e = (size_t)(ebase + (v >> 1));
        if (v & 1) outi[e * F + ox] = accO[j];
        else       outr[e * F + ox] = accO[j];
    }
}

extern "C" void kernel_launch(void* const* d_in, const int* in_sizes, int n_in,
                              void* d_out, int out_size, void* d_ws, size_t ws_size,
                              hipStream_t stream) {
    const void* node_real = d_in[0];
    const void* node_imag = d_in[1];
    const void* edge_real = d_in[2];
    const void* edge_imag = d_in[3];
    const int*  edge_index = (const int*)d_in[4];
    const void* Wn = d_in[5];
    const void* bn = d_in[6];
    const void* We = d_in[7];
    const void* be = d_in[8];
    const void* node_W = d_in[9];
    const void* node_b = d_in[10];
    const void* node_alpha = d_in[11];
    const void* node_outW = d_in[12];
    const void* node_outb = d_in[13];
    const void* edge_W = d_in[14];
    const void* edge_b = d_in[15];
    const void* edge_alpha = d_in[16];
    const void* edge_outW = d_in[17];
    const void* edge_outb = d_in[18];

    // workspace: [flags (64B) | xr NN*HD f32 | xi NN*HD f32] = 38.4 MB + 64 B
    int*   flags = (int*)d_ws;
    float* xr = (float*)((char*)d_ws + 64);
    float* xi = xr + (size_t)NN * HD;

    // outputs are FLOAT32 (reference output dtype), concatenated (hr, hi, outr, outi)
    float* out = (float*)d_out;
    float* o_hr = out;
    float* o_hi = o_hr + (size_t)NN * F;
    float* o_outr = o_hi + (size_t)NN * F;
    float* o_outi = o_outr + (size_t)NE * F;

    hipMemsetAsync(xr, 0, (size_t)2 * NN * HD * sizeof(float), stream);

    detect_meta<<<1, 256, 0, stream>>>(edge_index, (const unsigned*)node_real, flags);
    encode_nodes<<<(NN + 3) / 4, dim3(64, 4), 0, stream>>>(
        node_real, node_imag, Wn, bn, flags, xr, xi);
    encode_scatter_edges<<<NE / SE, 256, 0, stream>>>(
        edge_real, edge_imag, We, be, edge_index, flags, xr, xi);
    node_mlp<<<(NN + NB - 1) / NB, 192, 0, stream>>>(
        xr, xi, node_W, node_b, node_alpha, node_outW, node_outb, flags, o_hr, o_hi);
    edge_mlp<<<NE / EB2, 256, 0, stream>>>(
        edge_real, edge_imag, We, be, edge_index, flags, o_hr, o_hi,
        edge_W, edge_b, edge_alpha, edge_outW, edge_outb, o_outr, o_outi);
}

// Round 12
// 4368.207 us; speedup vs baseline: 4.6774x; 4.6774x over previous
//
#include <hip/hip_runtime.h>

#define NN 25000
#define NE 200000
#define F 64
#define HD 192
#define NL 3
#define NB 8    // nodes per block in node_mlp
#define SE 16   // edges per block in encode_scatter_edges
#define FP (F + 1)

// edge_mlp tiling
#define EB2 16          // edges per block (32 vectors: real+imag)
#define KC 16           // k-chunk staged in LDS
#define WST 20          // LDS chunk row stride (20 floats: bank-balanced, 16B-aligned)
#define NCH (HD / KC)   // 12 chunks per 192-wide layer

typedef unsigned short bfu;

__device__ __forceinline__ float bf2f(bfu u) { return __uint_as_float(((unsigned)u) << 16); }
// dual-dtype float loads: isf32 is wave-uniform (runtime-detected)
__device__ __forceinline__ float loadf(const void* p, size_t i, int isf32) {
    return isf32 ? ((const float*)p)[i] : bf2f(((const bfu*)p)[i]);
}
__device__ __forceinline__ float4 load4(const void* p, size_t i4, int isf32) {
    if (isf32) return ((const float4*)p)[i4];
    ushort4 u = ((const ushort4*)p)[i4];
    return make_float4(bf2f(u.x), bf2f(u.y), bf2f(u.z), bf2f(u.w));
}

// ---- runtime metadata detection ----
// flags[0]: edge_index is int32 pairs (1) vs int64 values (0).
// flags[1]: float tensors are f32 (1) vs bf16 (0).
__global__ void detect_meta(const int* __restrict__ idx, const unsigned* __restrict__ fdata,
                            int* __restrict__ flags) {
    __shared__ int s_or[256];
    __shared__ int s_cnt[256];
    int t = threadIdx.x;
    int v = 0;
    for (int j = t; j < 4096; j += 256) v |= idx[2 * j + 1];
    int c = 0;
    for (int j = t; j < 2048; j += 256) {
        unsigned e = (fdata[j] >> 7) & 0xFFu;
        c += (e >= 100u && e <= 140u) ? 1 : 0;
    }
    s_or[t] = v; s_cnt[t] = c;
    __syncthreads();
    for (int s = 128; s > 0; s >>= 1) {
        if (t < s) { s_or[t] |= s_or[t + s]; s_cnt[t] += s_cnt[t + s]; }
        __syncthreads();
    }
    if (t == 0) { flags[0] = (s_or[0] != 0); flags[1] = (s_cnt[0] < 1024); }
}

__device__ __forceinline__ void load_edge(const int* __restrict__ idx, int i32flag, int e,
                                          int& row, int& col) {
    if (i32flag) { row = idx[2 * e]; col = idx[2 * e + 1]; }
    else         { row = idx[4 * e]; col = idx[4 * e + 2]; }
}

// ---- node encoder: xr[n,0:64] = node_real @ Wn^T + bn (likewise imag) ----
__global__ __launch_bounds__(256) void encode_nodes(
    const void* __restrict__ xr_in, const void* __restrict__ xi_in,
    const void* __restrict__ W, const void* __restrict__ b,
    const int* __restrict__ flags,
    float* __restrict__ xr, float* __restrict__ xi)
{
    __shared__ float Ws[F * FP];
    __shared__ float bs[F];
    __shared__ float xsr[4][F], xsi[4][F];
    int isf32 = flags[1];
    int t = threadIdx.y * 64 + threadIdx.x;
    for (int k = t; k < F * F; k += 256) Ws[(k >> 6) * FP + (k & 63)] = loadf(W, k, isf32);
    if (t < F) bs[t] = loadf(b, t, isf32);
    int n = blockIdx.x * 4 + threadIdx.y;
    int o = threadIdx.x;
    if (n < NN) {
        xsr[threadIdx.y][o] = loadf(xr_in, (size_t)n * F + o, isf32);
        xsi[threadIdx.y][o] = loadf(xi_in, (size_t)n * F + o, isf32);
    }
    __syncthreads();
    if (n >= NN) return;
    float ar = bs[o], ai = bs[o];
    const float* wrow = &Ws[o * FP];
    #pragma unroll 8
    for (int i = 0; i < F; i++) {
        ar += xsr[threadIdx.y][i] * wrow[i];
        ai += xsi[threadIdx.y][i] * wrow[i];
    }
    xr[(size_t)n * HD + o] = ar;
    xi[(size_t)n * HD + o] = ai;
}

// ---- fused edge encode + scatter:
//   xr[row,128+f] += (We@e+be)[f];  xr[row,64+f] += xr[col,f]  (cols 0:64 = encoded nodes)
__global__ __launch_bounds__(256) void encode_scatter_edges(
    const void* __restrict__ edge_real, const void* __restrict__ edge_imag,
    const void* __restrict__ We, const void* __restrict__ be,
    const int* __restrict__ idx, const int* __restrict__ flags,
    float* __restrict__ xr, float* __restrict__ xi)
{
    __shared__ float Ws[F * FP];
    __shared__ float bs[F];
    __shared__ float xinr[SE][F], xini[SE][F];
    __shared__ int rows[SE], cols[SE];
    int isf32 = flags[1];
    int t = threadIdx.x;
    int ebase = blockIdx.x * SE;
    for (int k = t; k < F * F; k += 256) Ws[(k >> 6) * FP + (k & 63)] = loadf(We, k, isf32);
    if (t < F) bs[t] = loadf(be, t, isf32);
    if (t < SE) {
        int r, c;
        load_edge(idx, flags[0], ebase + t, r, c);
        rows[t] = r; cols[t] = c;
    }
    for (int j = t; j < SE * F; j += 256) {
        int nb = j >> 6, f = j & 63;
        xinr[nb][f] = loadf(edge_real, (size_t)(ebase + nb) * F + f, isf32);
        xini[nb][f] = loadf(edge_imag, (size_t)(ebase + nb) * F + f, isf32);
    }
    __syncthreads();
    for (int j = t; j < SE * F; j += 256) {
        int nb = j >> 6, f = j & 63;
        float ar = bs[f], ai = bs[f];
        const float* wrow = &Ws[f * FP];
        #pragma unroll 8
        for (int i = 0; i < F; i++) {
            ar += wrow[i] * xinr[nb][i];
            ai += wrow[i] * xini[nb][i];
        }
        int row = rows[nb], col = cols[nb];
        atomicAdd(&xr[(size_t)row * HD + 128 + f], ar);
        atomicAdd(&xi[(size_t)row * HD + 128 + f], ai);
        atomicAdd(&xr[(size_t)row * HD + 64 + f], xr[(size_t)col * HD + f]);
        atomicAdd(&xi[(size_t)row * HD + 64 + f], xi[(size_t)col * HD + f]);
    }
}

// ---- node MLP: 8 nodes/block; writes h (f32) into d_out ----
__global__ __launch_bounds__(192) void node_mlp(
    const float* __restrict__ xr, const float* __restrict__ xi,
    const void* __restrict__ W, const void* __restrict__ b, const void* __restrict__ alpha,
    const void* __restrict__ Wout, const void* __restrict__ bout,
    const int* __restrict__ flags,
    float* __restrict__ o_hr, float* __restrict__ o_hi)
{
    __shared__ float xs[2 * NB][HD];
    int isf32 = flags[1];
    int t = threadIdx.x;
    int nbase = blockIdx.x * NB;
    for (int j = t; j < NB * HD; j += 192) {
        int nb = j / HD, f = j % HD;
        int n = nbase + nb;
        float vr = 0.f, vi = 0.f;
        if (n < NN) { vr = xr[(size_t)n * HD + f]; vi = xi[(size_t)n * HD + f]; }
        xs[nb][f] = vr; xs[NB + nb][f] = vi;
    }
    __syncthreads();
    for (int l = 0; l < NL; l++) {
        size_t base4 = ((size_t)l * HD * HD + (size_t)t * HD) >> 2;
        float bb = loadf(b, l * HD + t, isf32);
        float acc[2 * NB];
        #pragma unroll
        for (int v = 0; v < 2 * NB; v++) acc[v] = bb;
        #pragma unroll 2
        for (int k = 0; k < HD / 4; k++) {
            float4 w = load4(W, base4 + k, isf32);
            #pragma unroll
            for (int v = 0; v < 2 * NB; v++)
                acc[v] += xs[v][4 * k] * w.x + xs[v][4 * k + 1] * w.y
                        + xs[v][4 * k + 2] * w.z + xs[v][4 * k + 3] * w.w;
        }
        float a = loadf(alpha, l, isf32);
        __syncthreads();
        #pragma unroll
        for (int v = 0; v < 2 * NB; v++) { float x = acc[v]; xs[v][t] = x >= 0.f ? x : a * x; }
        __syncthreads();
    }
    if (t < F) {
        size_t base4 = ((size_t)t * HD) >> 2;
        float bb = loadf(bout, t, isf32);
        float acc[2 * NB];
        #pragma unroll
        for (int v = 0; v < 2 * NB; v++) acc[v] = bb;
        #pragma unroll 2
        for (int k = 0; k < HD / 4; k++) {
            float4 w = load4(Wout, base4 + k, isf32);
            #pragma unroll
            for (int v = 0; v < 2 * NB; v++)
                acc[v] += xs[v][4 * k] * w.x + xs[v][4 * k + 1] * w.y
                        + xs[v][4 * k + 2] * w.z + xs[v][4 * k + 3] * w.w;
        }
        #pragma unroll
        for (int nb = 0; nb < NB; nb++) {
            int n = nbase + nb;
            if (n < NN) {
                o_hr[(size_t)n * F + t] = acc[nb];
                o_hi[(size_t)n * F + t] = acc[NB + nb];
            }
        }
    }
}

// ---- edge MLP (register-tiled, LDS-staged weights) ----
// 256 threads, 16 edges (32 vectors) per block.
// thread (ox = t&63, vy = t>>6): owns outputs {ox, ox+64, ox+128} for vectors 8vy..8vy+7.
// NOTE: __launch_bounds__(256) ONLY — adding a min-waves/EU arg (256,3) capped VGPRs at 84
// and spilled the 24 accumulators to scratch: 100 GB HBM traffic, 6x regression (round-7 PMC).
// Occupancy is LDS-bound at 3 blocks/CU regardless, so the cap bought nothing.
__global__ __launch_bounds__(256) void edge_mlp(
    const void* __restrict__ edge_real, const void* __restrict__ edge_imag,
    const void* __restrict__ We, const void* __restrict__ be,
    const int* __restrict__ idx, const int* __restrict__ flags,
    const float* __restrict__ o_hr, const float* __restrict__ o_hi,
    const void* __restrict__ W, const void* __restrict__ b, const void* __restrict__ alpha,
    const void* __restrict__ Wout, const void* __restrict__ bout,
    float* __restrict__ outr, float* __restrict__ outi)
{
    __shared__ float Wbuf[F * FP];          // 4160 floats: encoder [64][65], then chunks [192][20]
    __shared__ float bs[F];
    __shared__ float xs[2 * EB2][HD];       // 32 x 192
    __shared__ float xin[2][EB2][F];
    __shared__ int rows[EB2], cols[EB2];
    int isf32 = flags[1];
    int t = threadIdx.x;
    int ebase = blockIdx.x * EB2;
    int vy = t >> 6;        // 0..3 : vector group (wave id)
    int ox = t & 63;        // 0..63: output lane

    // ---- prologue: encoder weights + inputs + edge indices ----
    for (int k = t; k < F * F; k += 256) Wbuf[(k >> 6) * FP + (k & 63)] = loadf(We, k, isf32);
    if (t < F) bs[t] = loadf(be, t, isf32);
    if (t < EB2) {
        int r, c;
        load_edge(idx, flags[0], ebase + t, r, c);
        rows[t] = r; cols[t] = c;
    }
    for (int j = t; j < EB2 * F; j += 256) {
        int nb = j >> 6, f = j & 63;
        xin[0][nb][f] = loadf(edge_real, (size_t)(ebase + nb) * F + f, isf32);
        xin[1][nb][f] = loadf(edge_imag, (size_t)(ebase + nb) * F + f, isf32);
    }
    __syncthreads();
    // encoded edge feats -> xs[:,0:64]; gathered h[row],h[col] -> xs[:,64:192]
    // vector v = 2*edge_local + (0 real / 1 imag)
    for (int j = t; j < EB2 * F; j += 256) {
        int nb = j >> 6, f = j & 63;
        float ar = bs[f], ai = bs[f];
        const float* wrow = &Wbuf[f * FP];
        #pragma unroll 8
        for (int i = 0; i < F; i++) {
            ar += wrow[i] * xin[0][nb][i];
            ai += wrow[i] * xin[1][nb][i];
        }
        int r = rows[nb], cc = cols[nb];
        xs[2 * nb][f]     = ar;
        xs[2 * nb + 1][f] = ai;
        xs[2 * nb][F + f]         = o_hr[(size_t)r * F + f];
        xs[2 * nb + 1][F + f]     = o_hi[(size_t)r * F + f];
        xs[2 * nb][2 * F + f]     = o_hr[(size_t)cc * F + f];
        xs[2 * nb + 1][2 * F + f] = o_hi[(size_t)cc * F + f];
    }
    // no explicit barrier: the first chunk barrier below orders prologue writes/reads.

    const float* xgrp = &xs[8 * vy][0];

    // ---- 3 hidden layers ----
    #pragma unroll 1
    for (int l = 0; l < NL; l++) {
        float acc0[8], acc1[8], acc2[8];
        {
            float b0 = loadf(b, l * HD + ox, isf32);
            float b1 = loadf(b, l * HD + ox + 64, isf32);
            float b2 = loadf(b, l * HD + ox + 128, isf32);
            #pragma unroll
            for (int j = 0; j < 8; j++) { acc0[j] = b0; acc1[j] = b1; acc2[j] = b2; }
        }
        #pragma unroll 1
        for (int c = 0; c < NCH; c++) {
            // stage chunk: rows 0..191, cols c*16..c*16+15 ; 3 float4 per thread, 64B segments
            size_t wb = (size_t)l * (HD * HD / 4) + (size_t)c * (KC / 4);
            float4 p0 = load4(W, wb + (size_t)((t      ) >> 2) * (HD / 4) + ((t      ) & 3), isf32);
            float4 p1 = load4(W, wb + (size_t)((t + 256) >> 2) * (HD / 4) + ((t + 256) & 3), isf32);
            float4 p2 = load4(W, wb + (size_t)((t + 512) >> 2) * (HD / 4) + ((t + 512) & 3), isf32);
            __syncthreads();   // previous chunk's readers done
            *(float4*)&Wbuf[((t      ) >> 2) * WST + ((t      ) & 3) * 4] = p0;
            *(float4*)&Wbuf[((t + 256) >> 2) * WST + ((t + 256) & 3) * 4] = p1;
            *(float4*)&Wbuf[((t + 512) >> 2) * WST + ((t + 512) & 3) * 4] = p2;
            __syncthreads();   // chunk ready
            const float* xb = xgrp + c * KC;
            #pragma unroll
            for (int k4 = 0; k4 < KC / 4; k4++) {
                float4 w0 = *(const float4*)&Wbuf[(ox      ) * WST + 4 * k4];
                float4 w1 = *(const float4*)&Wbuf[(ox +  64) * WST + 4 * k4];
                float4 w2 = *(const float4*)&Wbuf[(ox + 128) * WST + 4 * k4];
                #pragma unroll
                for (int j = 0; j < 8; j++) {
                    float4 xv = *(const float4*)(xb + j * HD + 4 * k4);
                    acc0[j] += xv.x * w0.x + xv.y * w0.y + xv.z * w0.z + xv.w * w0.w;
                    acc1[j] += xv.x * w1.x + xv.y * w1.y + xv.z * w1.z + xv.w * w1.w;
                    acc2[j] += xv.x * w2.x + xv.y * w2.y + xv.z * w2.z + xv.w * w2.w;
                }
            }
        }
        float a = loadf(alpha, l, isf32);
        #pragma unroll
        for (int j = 0; j < 8; j++) {     // xs rows 8vy..8vy+7 are wave-private: no barrier
            float x0 = acc0[j], x1 = acc1[j], x2 = acc2[j];
            xs[8 * vy + j][ox      ] = x0 >= 0.f ? x0 : a * x0;
            xs[8 * vy + j][ox +  64] = x1 >= 0.f ? x1 : a * x1;
            xs[8 * vy + j][ox + 128] = x2 >= 0.f ? x2 : a * x2;
        }
    }

    // ---- output layer: 64 outputs; thread (ox,vy) -> output ox of its 8 vectors ----
    float accO[8];
    {
        float bo = loadf(bout, ox, isf32);
        #pragma unroll
        for (int j = 0; j < 8; j++) accO[j] = bo;
    }
    #pragma unroll 1
    for (int c = 0; c < NCH; c++) {
        float4 p0 = load4(Wout, (size_t)(t >> 2) * (HD / 4) + (size_t)c * (KC / 4) + (t & 3), isf32);
        __syncthreads();
        *(float4*)&Wbuf[(t >> 2) * WST + (t & 3) * 4] = p0;
        __syncthreads();
        const float* xb = xgrp + c * KC;
        #pragma unroll
        for (int k4 = 0; k4 < KC / 4; k4++) {
            float4 w0 = *(const float4*)&Wbuf[ox * WST + 4 * k4];
            #pragma unroll
            for (int j = 0; j < 8; j++) {
                float4 xv = *(const float4*)(xb + j * HD + 4 * k4);
                accO[j] += xv.x * w0.x + xv.y * w0.y + xv.z * w0.z + xv.w * w0.w;
            }
        }
    }
    #pragma unroll
    for (int j = 0; j < 8; j++) {
        int v = 8 * vy + j;
        size_t e = (size_t)(ebase + (v >> 1));
        if (v & 1) outi[e * F + ox] = accO[j];
        else       outr[e * F + ox] = accO[j];
    }
}

extern "C" void kernel_launch(void* const* d_in, const int* in_sizes, int n_in,
                              void* d_out, int out_size, void* d_ws, size_t ws_size,
                              hipStream_t stream) {
    const void* node_real = d_in[0];
    const void* node_imag = d_in[1];
    const void* edge_real = d_in[2];
    const void* edge_imag = d_in[3];
    const int*  edge_index = (const int*)d_in[4];
    const void* Wn = d_in[5];
    const void* bn = d_in[6];
    const void* We = d_in[7];
    const void* be = d_in[8];
    const void* node_W = d_in[9];
    const void* node_b = d_in[10];
    const void* node_alpha = d_in[11];
    const void* node_outW = d_in[12];
    const void* node_outb = d_in[13];
    const void* edge_W = d_in[14];
    const void* edge_b = d_in[15];
    const void* edge_alpha = d_in[16];
    const void* edge_outW = d_in[17];
    const void* edge_outb = d_in[18];

    // workspace: [flags (64B) | xr NN*HD f32 | xi NN*HD f32] = 38.4 MB + 64 B
    int*   flags = (int*)d_ws;
    float* xr = (float*)((char*)d_ws + 64);
    float* xi = xr + (size_t)NN * HD;

    // outputs are FLOAT32 (reference output dtype), concatenated (hr, hi, outr, outi)
    float* out = (float*)d_out;
    float* o_hr = out;
    float* o_hi = o_hr + (size_t)NN * F;
    float* o_outr = o_hi + (size_t)NN * F;
    float* o_outi = o_outr + (size_t)NE * F;

    hipMemsetAsync(xr, 0, (size_t)2 * NN * HD * sizeof(float), stream);

    detect_meta<<<1, 256, 0, stream>>>(edge_index, (const unsigned*)node_real, flags);
    encode_nodes<<<(NN + 3) / 4, dim3(64, 4), 0, stream>>>(
        node_real, node_imag, Wn, bn, flags, xr, xi);
    encode_scatter_edges<<<NE / SE, 256, 0, stream>>>(
        edge_real, edge_imag, We, be, edge_index, flags, xr, xi);
    node_mlp<<<(NN + NB - 1) / NB, 192, 0, stream>>>(
        xr, xi, node_W, node_b, node_alpha, node_outW, node_outb, flags, o_hr, o_hi);
    edge_mlp<<<NE / EB2, 256, 0, stream>>>(
        edge_real, edge_imag, We, be, edge_index, flags, o_hr, o_hi,
        edge_W, edge_b, edge_alpha, edge_outW, edge_outb, o_outr, o_outi);
}

// Round 15
// 3260.887 us; speedup vs baseline: 6.2657x; 1.3396x over previous
//
#include <hip/hip_runtime.h>

#define NN 25000
#define NE 200000
#define F 64
#define HD 192
#define NL 3
#define NB 8    // nodes per block in node_mlp
#define SE 16   // edges per block in encode_scatter_edges
#define FP (F + 1)

// edge_mlp tiling
#define EB2 16          // edges per block (32 vectors: real+imag)
#define KC 16           // k-chunk staged in LDS
#define WST 20          // LDS chunk row stride (20 floats: bank-balanced, 16B-aligned)
#define NCH (HD / KC)   // 12 chunks per 192-wide layer

typedef unsigned short bfu;

__device__ __forceinline__ float bf2f(bfu u) { return __uint_as_float(((unsigned)u) << 16); }
// dual-dtype float loads: isf32 is wave-uniform (runtime-detected)
__device__ __forceinline__ float loadf(const void* p, size_t i, int isf32) {
    return isf32 ? ((const float*)p)[i] : bf2f(((const bfu*)p)[i]);
}
__device__ __forceinline__ float4 load4(const void* p, size_t i4, int isf32) {
    if (isf32) return ((const float4*)p)[i4];
    ushort4 u = ((const ushort4*)p)[i4];
    return make_float4(bf2f(u.x), bf2f(u.y), bf2f(u.z), bf2f(u.w));
}

// ---- runtime metadata detection ----
// flags[0]: edge_index is int32 pairs (1) vs int64 values (0).
// flags[1]: float tensors are f32 (1) vs bf16 (0).
__global__ void detect_meta(const int* __restrict__ idx, const unsigned* __restrict__ fdata,
                            int* __restrict__ flags) {
    __shared__ int s_or[256];
    __shared__ int s_cnt[256];
    int t = threadIdx.x;
    int v = 0;
    for (int j = t; j < 4096; j += 256) v |= idx[2 * j + 1];
    int c = 0;
    for (int j = t; j < 2048; j += 256) {
        unsigned e = (fdata[j] >> 7) & 0xFFu;
        c += (e >= 100u && e <= 140u) ? 1 : 0;
    }
    s_or[t] = v; s_cnt[t] = c;
    __syncthreads();
    for (int s = 128; s > 0; s >>= 1) {
        if (t < s) { s_or[t] |= s_or[t + s]; s_cnt[t] += s_cnt[t + s]; }
        __syncthreads();
    }
    if (t == 0) { flags[0] = (s_or[0] != 0); flags[1] = (s_cnt[0] < 1024); }
}

__device__ __forceinline__ void load_edge(const int* __restrict__ idx, int i32flag, int e,
                                          int& row, int& col) {
    if (i32flag) { row = idx[2 * e]; col = idx[2 * e + 1]; }
    else         { row = idx[4 * e]; col = idx[4 * e + 2]; }
}

// ---- node encoder: xr[n,0:64] = node_real @ Wn^T + bn (likewise imag) ----
__global__ __launch_bounds__(256) void encode_nodes(
    const void* __restrict__ xr_in, const void* __restrict__ xi_in,
    const void* __restrict__ W, const void* __restrict__ b,
    const int* __restrict__ flags,
    float* __restrict__ xr, float* __restrict__ xi)
{
    __shared__ float Ws[F * FP];
    __shared__ float bs[F];
    __shared__ float xsr[4][F], xsi[4][F];
    int isf32 = flags[1];
    int t = threadIdx.y * 64 + threadIdx.x;
    for (int k = t; k < F * F; k += 256) Ws[(k >> 6) * FP + (k & 63)] = loadf(W, k, isf32);
    if (t < F) bs[t] = loadf(b, t, isf32);
    int n = blockIdx.x * 4 + threadIdx.y;
    int o = threadIdx.x;
    if (n < NN) {
        xsr[threadIdx.y][o] = loadf(xr_in, (size_t)n * F + o, isf32);
        xsi[threadIdx.y][o] = loadf(xi_in, (size_t)n * F + o, isf32);
    }
    __syncthreads();
    if (n >= NN) return;
    float ar = bs[o], ai = bs[o];
    const float* wrow = &Ws[o * FP];
    #pragma unroll 8
    for (int i = 0; i < F; i++) {
        ar += xsr[threadIdx.y][i] * wrow[i];
        ai += xsi[threadIdx.y][i] * wrow[i];
    }
    xr[(size_t)n * HD + o] = ar;
    xi[(size_t)n * HD + o] = ai;
}

// ---- fused edge encode + scatter:
//   xr[row,128+f] += (We@e+be)[f];  xr[row,64+f] += xr[col,f]  (cols 0:64 = encoded nodes)
__global__ __launch_bounds__(256) void encode_scatter_edges(
    const void* __restrict__ edge_real, const void* __restrict__ edge_imag,
    const void* __restrict__ We, const void* __restrict__ be,
    const int* __restrict__ idx, const int* __restrict__ flags,
    float* __restrict__ xr, float* __restrict__ xi)
{
    __shared__ float Ws[F * FP];
    __shared__ float bs[F];
    __shared__ float xinr[SE][F], xini[SE][F];
    __shared__ int rows[SE], cols[SE];
    int isf32 = flags[1];
    int t = threadIdx.x;
    int ebase = blockIdx.x * SE;
    for (int k = t; k < F * F; k += 256) Ws[(k >> 6) * FP + (k & 63)] = loadf(We, k, isf32);
    if (t < F) bs[t] = loadf(be, t, isf32);
    if (t < SE) {
        int r, c;
        load_edge(idx, flags[0], ebase + t, r, c);
        rows[t] = r; cols[t] = c;
    }
    for (int j = t; j < SE * F; j += 256) {
        int nb = j >> 6, f = j & 63;
        xinr[nb][f] = loadf(edge_real, (size_t)(ebase + nb) * F + f, isf32);
        xini[nb][f] = loadf(edge_imag, (size_t)(ebase + nb) * F + f, isf32);
    }
    __syncthreads();
    for (int j = t; j < SE * F; j += 256) {
        int nb = j >> 6, f = j & 63;
        float ar = bs[f], ai = bs[f];
        const float* wrow = &Ws[f * FP];
        #pragma unroll 8
        for (int i = 0; i < F; i++) {
            ar += wrow[i] * xinr[nb][i];
            ai += wrow[i] * xini[nb][i];
        }
        int row = rows[nb], col = cols[nb];
        atomicAdd(&xr[(size_t)row * HD + 128 + f], ar);
        atomicAdd(&xi[(size_t)row * HD + 128 + f], ai);
        atomicAdd(&xr[(size_t)row * HD + 64 + f], xr[(size_t)col * HD + f]);
        atomicAdd(&xi[(size_t)row * HD + 64 + f], xi[(size_t)col * HD + f]);
    }
}

// ---- node MLP: 8 nodes/block; writes h (f32) into d_out ----
__global__ __launch_bounds__(192) void node_mlp(
    const float* __restrict__ xr, const float* __restrict__ xi,
    const void* __restrict__ W, const void* __restrict__ b, const void* __restrict__ alpha,
    const void* __restrict__ Wout, const void* __restrict__ bout,
    const int* __restrict__ flags,
    float* __restrict__ o_hr, float* __restrict__ o_hi)
{
    __shared__ float xs[2 * NB][HD];
    int isf32 = flags[1];
    int t = threadIdx.x;
    int nbase = blockIdx.x * NB;
    for (int j = t; j < NB * HD; j += 192) {
        int nb = j / HD, f = j % HD;
        int n = nbase + nb;
        float vr = 0.f, vi = 0.f;
        if (n < NN) { vr = xr[(size_t)n * HD + f]; vi = xi[(size_t)n * HD + f]; }
        xs[nb][f] = vr; xs[NB + nb][f] = vi;
    }
    __syncthreads();
    for (int l = 0; l < NL; l++) {
        size_t base4 = ((size_t)l * HD * HD + (size_t)t * HD) >> 2;
        float bb = loadf(b, l * HD + t, isf32);
        float acc[2 * NB];
        #pragma unroll
        for (int v = 0; v < 2 * NB; v++) acc[v] = bb;
        #pragma unroll 2
        for (int k = 0; k < HD / 4; k++) {
            float4 w = load4(W, base4 + k, isf32);
            #pragma unroll
            for (int v = 0; v < 2 * NB; v++)
                acc[v] += xs[v][4 * k] * w.x + xs[v][4 * k + 1] * w.y
                        + xs[v][4 * k + 2] * w.z + xs[v][4 * k + 3] * w.w;
        }
        float a = loadf(alpha, l, isf32);
        __syncthreads();
        #pragma unroll
        for (int v = 0; v < 2 * NB; v++) { float x = acc[v]; xs[v][t] = x >= 0.f ? x : a * x; }
        __syncthreads();
    }
    if (t < F) {
        size_t base4 = ((size_t)t * HD) >> 2;
        float bb = loadf(bout, t, isf32);
        float acc[2 * NB];
        #pragma unroll
        for (int v = 0; v < 2 * NB; v++) acc[v] = bb;
        #pragma unroll 2
        for (int k = 0; k < HD / 4; k++) {
            float4 w = load4(Wout, base4 + k, isf32);
            #pragma unroll
            for (int v = 0; v < 2 * NB; v++)
                acc[v] += xs[v][4 * k] * w.x + xs[v][4 * k + 1] * w.y
                        + xs[v][4 * k + 2] * w.z + xs[v][4 * k + 3] * w.w;
        }
        #pragma unroll
        for (int nb = 0; nb < NB; nb++) {
            int n = nbase + nb;
            if (n < NN) {
                o_hr[(size_t)n * F + t] = acc[nb];
                o_hi[(size_t)n * F + t] = acc[NB + nb];
            }
        }
    }
}

// ---- edge MLP (register-tiled, LDS-staged weights) ----
// 256 threads, 16 edges (32 vectors) per block.
// thread (ox = t&63, vy = t>>6): owns outputs {ox, ox+64, ox+128} for vectors 8vy..8vy+7.
// VGPR history (round-7/12 PMC): (256,3) -> compiler targeted 6 waves/EU, capped 84 VGPR,
//   spilled 24 accs -> 100 GB scratch traffic, 19.9 ms. No bound -> 136 VGPR, crosses the
//   128-VGPR occupancy step -> Occupancy 12%, 3.9 ms (concurrency-starved, no pipe >50%).
// (256,2): by round-7's empirical rule (compiler doubles the requested min waves/EU),
//   targets 4 waves/EU = cap 128 — at the step boundary, comfortably above the ~80 live regs.
__global__ __launch_bounds__(256, 2) void edge_mlp(
    const void* __restrict__ edge_real, const void* __restrict__ edge_imag,
    const void* __restrict__ We, const void* __restrict__ be,
    const int* __restrict__ idx, const int* __restrict__ flags,
    const float* __restrict__ o_hr, const float* __restrict__ o_hi,
    const void* __restrict__ W, const void* __restrict__ b, const void* __restrict__ alpha,
    const void* __restrict__ Wout, const void* __restrict__ bout,
    float* __restrict__ outr, float* __restrict__ outi)
{
    __shared__ float Wbuf[F * FP];          // 4160 floats: encoder [64][65], then chunks [192][20]
    __shared__ float bs[F];
    __shared__ float xs[2 * EB2][HD];       // 32 x 192
    __shared__ float xin[2][EB2][F];
    __shared__ int rows[EB2], cols[EB2];
    int isf32 = flags[1];
    int t = threadIdx.x;
    int ebase = blockIdx.x * EB2;
    int vy = t >> 6;        // 0..3 : vector group (wave id)
    int ox = t & 63;        // 0..63: output lane

    // ---- prologue: encoder weights + inputs + edge indices ----
    for (int k = t; k < F * F; k += 256) Wbuf[(k >> 6) * FP + (k & 63)] = loadf(We, k, isf32);
    if (t < F) bs[t] = loadf(be, t, isf32);
    if (t < EB2) {
        int r, c;
        load_edge(idx, flags[0], ebase + t, r, c);
        rows[t] = r; cols[t] = c;
    }
    for (int j = t; j < EB2 * F; j += 256) {
        int nb = j >> 6, f = j & 63;
        xin[0][nb][f] = loadf(edge_real, (size_t)(ebase + nb) * F + f, isf32);
        xin[1][nb][f] = loadf(edge_imag, (size_t)(ebase + nb) * F + f, isf32);
    }
    __syncthreads();
    // encoded edge feats -> xs[:,0:64]; gathered h[row],h[col] -> xs[:,64:192]
    // vector v = 2*edge_local + (0 real / 1 imag)
    for (int j = t; j < EB2 * F; j += 256) {
        int nb = j >> 6, f = j & 63;
        float ar = bs[f], ai = bs[f];
        const float* wrow = &Wbuf[f * FP];
        #pragma unroll 8
        for (int i = 0; i < F; i++) {
            ar += wrow[i] * xin[0][nb][i];
            ai += wrow[i] * xin[1][nb][i];
        }
        int r = rows[nb], cc = cols[nb];
        xs[2 * nb][f]     = ar;
        xs[2 * nb + 1][f] = ai;
        xs[2 * nb][F + f]         = o_hr[(size_t)r * F + f];
        xs[2 * nb + 1][F + f]     = o_hi[(size_t)r * F + f];
        xs[2 * nb][2 * F + f]     = o_hr[(size_t)cc * F + f];
        xs[2 * nb + 1][2 * F + f] = o_hi[(size_t)cc * F + f];
    }
    // no explicit barrier: the first chunk barrier below orders prologue writes/reads.

    const float* xgrp = &xs[8 * vy][0];

    // ---- 3 hidden layers ----
    #pragma unroll 1
    for (int l = 0; l < NL; l++) {
        float acc0[8], acc1[8], acc2[8];
        {
            float b0 = loadf(b, l * HD + ox, isf32);
            float b1 = loadf(b, l * HD + ox + 64, isf32);
            float b2 = loadf(b, l * HD + ox + 128, isf32);
            #pragma unroll
            for (int j = 0; j < 8; j++) { acc0[j] = b0; acc1[j] = b1; acc2[j] = b2; }
        }
        #pragma unroll 1
        for (int c = 0; c < NCH; c++) {
            // stage chunk: rows 0..191, cols c*16..c*16+15 ; 3 float4 per thread, 64B segments
            size_t wb = (size_t)l * (HD * HD / 4) + (size_t)c * (KC / 4);
            float4 p0 = load4(W, wb + (size_t)((t      ) >> 2) * (HD / 4) + ((t      ) & 3), isf32);
            float4 p1 = load4(W, wb + (size_t)((t + 256) >> 2) * (HD / 4) + ((t + 256) & 3), isf32);
            float4 p2 = load4(W, wb + (size_t)((t + 512) >> 2) * (HD / 4) + ((t + 512) & 3), isf32);
            __syncthreads();   // previous chunk's readers done
            *(float4*)&Wbuf[((t      ) >> 2) * WST + ((t      ) & 3) * 4] = p0;
            *(float4*)&Wbuf[((t + 256) >> 2) * WST + ((t + 256) & 3) * 4] = p1;
            *(float4*)&Wbuf[((t + 512) >> 2) * WST + ((t + 512) & 3) * 4] = p2;
            __syncthreads();   // chunk ready
            const float* xb = xgrp + c * KC;
            #pragma unroll
            for (int k4 = 0; k4 < KC / 4; k4++) {
                float4 w0 = *(const float4*)&Wbuf[(ox      ) * WST + 4 * k4];
                float4 w1 = *(const float4*)&Wbuf[(ox +  64) * WST + 4 * k4];
                float4 w2 = *(const float4*)&Wbuf[(ox + 128) * WST + 4 * k4];
                #pragma unroll
                for (int j = 0; j < 8; j++) {
                    float4 xv = *(const float4*)(xb + j * HD + 4 * k4);
                    acc0[j] += xv.x * w0.x + xv.y * w0.y + xv.z * w0.z + xv.w * w0.w;
                    acc1[j] += xv.x * w1.x + xv.y * w1.y + xv.z * w1.z + xv.w * w1.w;
                    acc2[j] += xv.x * w2.x + xv.y * w2.y + xv.z * w2.z + xv.w * w2.w;
                }
            }
        }
        float a = loadf(alpha, l, isf32);
        #pragma unroll
        for (int j = 0; j < 8; j++) {     // xs rows 8vy..8vy+7 are wave-private: no barrier
            float x0 = acc0[j], x1 = acc1[j], x2 = acc2[j];
            xs[8 * vy + j][ox      ] = x0 >= 0.f ? x0 : a * x0;
            xs[8 * vy + j][ox +  64] = x1 >= 0.f ? x1 : a * x1;
            xs[8 * vy + j][ox + 128] = x2 >= 0.f ? x2 : a * x2;
        }
    }

    // ---- output layer: 64 outputs; thread (ox,vy) -> output ox of its 8 vectors ----
    float accO[8];
    {
        float bo = loadf(bout, ox, isf32);
        #pragma unroll
        for (int j = 0; j < 8; j++) accO[j] = bo;
    }
    #pragma unroll 1
    for (int c = 0; c < NCH; c++) {
        float4 p0 = load4(Wout, (size_t)(t >> 2) * (HD / 4) + (size_t)c * (KC / 4) + (t & 3), isf32);
        __syncthreads();
        *(float4*)&Wbuf[(t >> 2) * WST + (t & 3) * 4] = p0;
        __syncthreads();
        const float* xb = xgrp + c * KC;
        #pragma unroll
        for (int k4 = 0; k4 < KC / 4; k4++) {
            float4 w0 = *(const float4*)&Wbuf[ox * WST + 4 * k4];
            #pragma unroll
            for (int j = 0; j < 8; j++) {
                float4 xv = *(const float4*)(xb + j * HD + 4 * k4);
                accO[j] += xv.x * w0.x + xv.y * w0.y + xv.z * w0.z + xv.w * w0.w;
            }
        }
    }
    #pragma unroll
    for (int j = 0; j < 8; j++) {
        int v = 8 * vy + j;
        size_t e = (size_t)(ebase + (v >> 1));
        if (v & 1) outi[e * F + ox] = accO[j];
        else       outr[e * F + ox] = accO[j];
    }
}

extern "C" void kernel_launch(void* const* d_in, const int* in_sizes, int n_in,
                              void* d_out, int out_size, void* d_ws, size_t ws_size,
                              hipStream_t stream) {
    const void* node_real = d_in[0];
    const void* node_imag = d_in[1];
    const void* edge_real = d_in[2];
    const void* edge_imag = d_in[3];
    const int*  edge_index = (const int*)d_in[4];
    const void* Wn = d_in[5];
    const void* bn = d_in[6];
    const void* We = d_in[7];
    const void* be = d_in[8];
    const void* node_W = d_in[9];
    const void* node_b = d_in[10];
    const void* node_alpha = d_in[11];
    const void* node_outW = d_in[12];
    const void* node_outb = d_in[13];
    const void* edge_W = d_in[14];
    const void* edge_b = d_in[15];
    const void* edge_alpha = d_in[16];
    const void* edge_outW = d_in[17];
    const void* edge_outb = d_in[18];

    // workspace: [flags (64B) | xr NN*HD f32 | xi NN*HD f32] = 38.4 MB + 64 B
    int*   flags = (int*)d_ws;
    float* xr = (float*)((char*)d_ws + 64);
    float* xi = xr + (size_t)NN * HD;

    // outputs are FLOAT32 (reference output dtype), concatenated (hr, hi, outr, outi)
    float* out = (float*)d_out;
    float* o_hr = out;
    float* o_hi = o_hr + (size_t)NN * F;
    float* o_outr = o_hi + (size_t)NN * F;
    float* o_outi = o_outr + (size_t)NE * F;

    hipMemsetAsync(xr, 0, (size_t)2 * NN * HD * sizeof(float), stream);

    detect_meta<<<1, 256, 0, stream>>>(edge_index, (const unsigned*)node_real, flags);
    encode_nodes<<<(NN + 3) / 4, dim3(64, 4), 0, stream>>>(
        node_real, node_imag, Wn, bn, flags, xr, xi);
    encode_scatter_edges<<<NE / SE, 256, 0, stream>>>(
        edge_real, edge_imag, We, be, edge_index, flags, xr, xi);
    node_mlp<<<(NN + NB - 1) / NB, 192, 0, stream>>>(
        xr, xi, node_W, node_b, node_alpha, node_outW, node_outb, flags, o_hr, o_hi);
    edge_mlp<<<NE / EB2, 256, 0, stream>>>(
        edge_real, edge_imag, We, be, edge_index, flags, o_hr, o_hi,
        edge_W, edge_b, edge_alpha, edge_outW, edge_outb, o_outr, o_outi);
}